// Round 9
// baseline (403.027 us; speedup 1.0000x reference)
//
#include <hip/hip_runtime.h>
#include <hip/hip_bf16.h>

#define N_NODES 100000
#define N_EDGES 1600000
#define IN_F 128
#define C1 64      // HEADS*HID
#define NC 16      // classes / layer2 width

#define SCAN_TILE 1024
#define SCAN_NB ((N_NODES + SCAN_TILE - 1) / SCAN_TILE)   // 98 blocks
#define GB1_NB (N_NODES / 32)                             // 3125 blocks, 32 nodes each
#define HIST_NB ((N_EDGES + 1023) / 1024)                 // 1563 (scatter grid)

typedef __attribute__((ext_vector_type(8))) short short8;
typedef __attribute__((ext_vector_type(4))) float f32x4;

__device__ __forceinline__ float lrelu(float x) { return fmaxf(x, 0.2f * x); }
__device__ __forceinline__ float selh(float4 v, int h) {
    return (h == 0) ? v.x : (h == 1) ? v.y : (h == 2) ? v.z : v.w;
}
// bf16 pack (round-to-nearest-even) / unpack helpers
__device__ __forceinline__ unsigned bf16pk(float a, float b) {
    unsigned ua = __float_as_uint(a), ub = __float_as_uint(b);
    ua = (ua + 0x7FFFu + ((ua >> 16) & 1u)) >> 16;
    ub = (ub + 0x7FFFu + ((ub >> 16) & 1u)) >> 16;
    return ua | (ub << 16);
}
__device__ __forceinline__ float bflo(unsigned u) { return __uint_as_float(u << 16); }
__device__ __forceinline__ float bfhi(unsigned u) { return __uint_as_float(u & 0xFFFF0000u); }

// ---------------- fused: histogram interleaved INTO layer1 MFMA GEMM ---------
// r8 post-mortem: MFMA made compute free but kernel stuck at 77us — the
// barrier (vmcnt(0) drain) was waiting on 2 ATOMIC ROUND-TRIPS per thread
// (rank needed the returned value), and the random RMW writebacks added
// ~50MB of HBM write traffic. Now the histogram atomic is FIRE-AND-FORGET
// (result unused -> non-returning global_atomic_add, nothing to drain) and
// rank is deleted; the scatter recovers positions from a cursor array.
__global__ __launch_bounds__(256) void k_hist_gemm1(
    const int* __restrict__ e_dst, int* __restrict__ deg,
    const float* __restrict__ x, const float* __restrict__ W1,
    const float* __restrict__ att_src1, const float* __restrict__ att_dst1,
    unsigned* __restrict__ h1p, float* __restrict__ a_src1, float* __restrict__ a_dst1) {
    __shared__ __align__(16) unsigned xBSu[32 * 68];   // 8.7 KB: [32 rows][68 u32 = 136 bf16]
    __shared__ __align__(16) unsigned wTu[64 * 68];    // 17.4 KB: [64 cols][68 u32 = 136 bf16]
    int tid = threadIdx.x;

    // ---- hist: 2 edges per thread, exact coverage (3125*512 == E), no return
    int e0 = blockIdx.x * 512 + tid;
    atomicAdd(&deg[e_dst[e0]], 1);                  // fire-and-forget
    atomicAdd(&deg[e_dst[e0 + 256]], 1);

    int node0 = blockIdx.x * 32;

    // ---- stage x tile (32 rows x 128) -> bf16, while atomics are in flight
#pragma unroll
    for (int ii = 0; ii < 4; ii++) {                // 1024 float4s, 4/thread
        int i = tid + ii * 256;
        int r = i >> 5, c4 = (i & 31) << 2;         // c4 = k, multiple of 4
        float4 v = *(const float4*)&x[(node0 + r) * IN_F + c4];
        *(uint2*)&xBSu[r * 68 + (c4 >> 1)] =
            make_uint2(bf16pk(v.x, v.y), bf16pk(v.z, v.w));
    }
    // ---- stage W1 transposed -> bf16: wT[col][k], u32 kp holds k=2kp,2kp+1
#pragma unroll
    for (int ii = 0; ii < 4; ii++) {
        int kp = (tid >> 4) + ii * 16;              // k-pair 0..63
        int n0 = (tid & 15) << 2;
        int k = kp << 1;
        float4 r0 = *(const float4*)&W1[k * C1 + n0];
        float4 r1 = *(const float4*)&W1[(k + 1) * C1 + n0];
        wTu[(n0 + 0) * 68 + kp] = bf16pk(r0.x, r1.x);
        wTu[(n0 + 1) * 68 + kp] = bf16pk(r0.y, r1.y);
        wTu[(n0 + 2) * 68 + kp] = bf16pk(r0.z, r1.z);
        wTu[(n0 + 3) * 68 + kp] = bf16pk(r0.w, r1.w);
    }
    __syncthreads();

    // ---- MFMA K-loop: wave (wm,wn): rows 16*wm.., cols 32*wn..
    int wid = tid >> 6, l = tid & 63;
    int wm = wid & 1, wn = wid >> 1;
    int myc = l & 15;
    int koff = (l >> 4) << 3;                       // 8*(l>>4)
    const unsigned short* xu = (const unsigned short*)xBSu;
    const unsigned short* wu = (const unsigned short*)wTu;
    int arow = 16 * wm + myc;
    int bcol = 32 * wn + myc;
    f32x4 acc0 = {0.f, 0.f, 0.f, 0.f}, acc1 = acc0;
#pragma unroll
    for (int ks = 0; ks < 4; ks++) {
        int k0 = ks * 32 + koff;
        short8 af  = *(const short8*)&xu[arow * 136 + k0];
        short8 bf0 = *(const short8*)&wu[bcol * 136 + k0];
        short8 bf1 = *(const short8*)&wu[(bcol + 16) * 136 + k0];
        acc0 = __builtin_amdgcn_mfma_f32_16x16x32_bf16(af, bf0, acc0, 0, 0, 0);
        acc1 = __builtin_amdgcn_mfma_f32_16x16x32_bf16(af, bf1, acc1, 0, 0, 0);
    }

    // ---- epilogue from C frags: h1p bf16 pack + att dots (per-head = per-tile)
    int rbase = (l >> 4) << 2;
#pragma unroll
    for (int t = 0; t < 2; t++) {
        f32x4 av = t ? acc1 : acc0;
        int cb = 32 * wn + 16 * t;                  // tile col base; head = cb/16
        int head = cb >> 4;
        float sv = att_src1[cb + myc];
        float dv = att_dst1[cb + myc];
#pragma unroll
        for (int i = 0; i < 4; i++) {
            float v = av[i];
            int node = node0 + 16 * wm + rbase + i;
            float vp = __shfl_xor(v, 1);            // partner col's value
            if ((l & 1) == 0)
                h1p[node * 32 + (cb >> 1) + (myc >> 1)] = bf16pk(v, vp);
            float ps = v * sv, pd = v * dv;
            ps += __shfl_xor(ps, 1); ps += __shfl_xor(ps, 2);
            ps += __shfl_xor(ps, 4); ps += __shfl_xor(ps, 8);
            pd += __shfl_xor(pd, 1); pd += __shfl_xor(pd, 2);
            pd += __shfl_xor(pd, 4); pd += __shfl_xor(pd, 8);
            if (myc == 0) {
                a_src1[node * 4 + head] = ps;
                a_dst1[node * 4 + head] = pd;
            }
        }
    }
}

// pass 1: per-block sums of deg (1024 elems per 256-thread block)
__global__ __launch_bounds__(256) void k_scan1(const int* __restrict__ deg,
                                               int* __restrict__ partial) {
    __shared__ int wsum[4];
    int tid = threadIdx.x;
    int i0 = blockIdx.x * SCAN_TILE + tid * 4;
    int s = 0;
#pragma unroll
    for (int j = 0; j < 4; j++) { int i = i0 + j; if (i < N_NODES) s += deg[i]; }
    for (int off = 32; off; off >>= 1) s += __shfl_xor(s, off);
    if ((tid & 63) == 0) wsum[tid >> 6] = s;
    __syncthreads();
    if (tid == 0) partial[blockIdx.x] = wsum[0] + wsum[1] + wsum[2] + wsum[3];
}

// pass 2: exclusive scan of the 98 partials (single tiny block)
__global__ void k_scan2(const int* __restrict__ partial, int* __restrict__ pscan,
                        int* __restrict__ rowptr) {
    __shared__ int buf[128];
    int tid = threadIdx.x;
    int v = (tid < SCAN_NB) ? partial[tid] : 0;
    buf[tid] = v;
    __syncthreads();
    for (int d = 1; d < 128; d <<= 1) {
        int t = (tid >= d) ? buf[tid - d] : 0;
        __syncthreads();
        buf[tid] += t;
        __syncthreads();
    }
    if (tid < SCAN_NB) pscan[tid] = buf[tid] - v;    // exclusive
    if (tid == 0) rowptr[N_NODES] = N_EDGES;         // total is static
}

// pass 3: block-local exclusive scan + block offset -> rowptr AND cursor copy
__global__ __launch_bounds__(256) void k_scan3(const int* __restrict__ deg,
                                               const int* __restrict__ pscan,
                                               int* __restrict__ rowptr,
                                               int* __restrict__ cursor) {
    __shared__ int wsum[4];
    int tid = threadIdx.x, lane = tid & 63, wave = tid >> 6;
    int i0 = blockIdx.x * SCAN_TILE + tid * 4;
    int v0 = 0, v1 = 0, v2 = 0, v3 = 0;
    if (i0 + 0 < N_NODES) v0 = deg[i0 + 0];
    if (i0 + 1 < N_NODES) v1 = deg[i0 + 1];
    if (i0 + 2 < N_NODES) v2 = deg[i0 + 2];
    if (i0 + 3 < N_NODES) v3 = deg[i0 + 3];
    int s0 = v0, s1 = s0 + v1, s2 = s1 + v2, s3 = s2 + v3;   // thread-local inclusive
    int t = s3;                                              // wave inclusive scan
    for (int off = 1; off < 64; off <<= 1) {
        int u = __shfl_up(t, off);
        if (lane >= off) t += u;
    }
    if (lane == 63) wsum[wave] = t;
    __syncthreads();
    int woff = 0;
    for (int w = 0; w < wave; w++) woff += wsum[w];
    int base = pscan[blockIdx.x] + woff + (t - s3);          // exclusive prefix
    if (i0 + 0 < N_NODES) { rowptr[i0 + 0] = base;      cursor[i0 + 0] = base; }
    if (i0 + 1 < N_NODES) { rowptr[i0 + 1] = base + s0; cursor[i0 + 1] = base + s0; }
    if (i0 + 2 < N_NODES) { rowptr[i0 + 2] = base + s1; cursor[i0 + 2] = base + s1; }
    if (i0 + 3 < N_NODES) { rowptr[i0 + 3] = base + s2; cursor[i0 + 3] = base + s2; }
}

// cursor-based scatter: position = atomic bump of this dst's cursor
__global__ __launch_bounds__(256) void k_scatter(
    const int* __restrict__ e_src, const int* __restrict__ e_dst,
    int* __restrict__ cursor, int* __restrict__ csr_src) {
    int e0 = blockIdx.x * 1024 + threadIdx.x;
#pragma unroll
    for (int j = 0; j < 4; j++) {
        int e = e0 + j * 256;
        if (e < N_EDGES) {
            int pos = atomicAdd(&cursor[e_dst[e]], 1);
            csr_src[pos] = e_src[e];
        }
    }
}

// ---------------- layer 1 segment-softmax + aggregate ------------------------
// 16-lane group per node; packed-bf16 h1 gather (8B/lane). Unchanged from r7.
__global__ __launch_bounds__(256) void k_agg1(
    const unsigned* __restrict__ h1p, const float* __restrict__ a_src1,
    const float* __restrict__ a_dst1, const int* __restrict__ rowptr,
    const int* __restrict__ csr_src, const float* __restrict__ b1,
    const float* __restrict__ W2, const float* __restrict__ att_src2,
    const float* __restrict__ att_dst2,
    float* __restrict__ out_emb, float* __restrict__ h2,
    float* __restrict__ a_src2, float* __restrict__ a_dst2) {
    __shared__ int   srcS[16][17];                 // [group][edge] = src row byte off
    __shared__ __align__(16) float wW[16][17][4];  // [group][edge][head]
    __shared__ __align__(16) float w2S[C1 * NC];   // 4 KB [k][c]
    __shared__ float aS2[NC], aD2[NC];
    int tid = threadIdx.x;
    int g  = tid >> 4;                              // group in block (0..15)
    int gl = tid & 15;                              // lane in group
    int hl = gl >> 2;                               // head of my 4 owned cols
    int node = blockIdx.x * 16 + g;
    const char* h1b = (const char*)h1p;
    int laneoff = gl << 3;                          // byte offset of my 4 bf16 cols

    if (tid < (C1 * NC) / 4)
        *(float4*)&w2S[tid * 4] = *(const float4*)&W2[tid * 4];
    if (tid < NC) { aS2[tid] = att_src2[tid]; aD2[tid] = att_dst2[tid]; }

    int rs  = rowptr[node];
    int deg = rowptr[node + 1] - rs;

    float4 ad4 = *(const float4*)&a_dst1[node * 4];  // broadcast within group
    float w0h = __expf(lrelu(a_src1[node * 4 + hl] + selh(ad4, hl)));  // self weight, my head

    uint2 sp = *(const uint2*)(h1b + (unsigned)(node * 128 + laneoff));
    float4 acc = {w0h * bflo(sp.x), w0h * bfhi(sp.x),
                  w0h * bflo(sp.y), w0h * bfhi(sp.y)};
    float4 sac4 = {0.f, 0.f, 0.f, 0.f};             // per-lane partial denominator

    for (int base = 0; base < deg; base += 16) {    // 16 edges per group-chunk
        int idx = base + gl;
        int s_l = 0;
        float4 w4 = {0.f, 0.f, 0.f, 0.f};
        if (idx < deg) {                            // lane-parallel weight compute
            s_l = csr_src[rs + idx];
            float4 as = *(const float4*)&a_src1[s_l * 4];
            w4.x = __expf(lrelu(as.x + ad4.x));
            w4.y = __expf(lrelu(as.y + ad4.y));
            w4.z = __expf(lrelu(as.z + ad4.z));
            w4.w = __expf(lrelu(as.w + ad4.w));
        }
        sac4.x += w4.x; sac4.y += w4.y; sac4.z += w4.z; sac4.w += w4.w;
        srcS[g][gl] = s_l << 7;                     // bf16 row byte offset (128B)
        *(float4*)&wW[g][gl][0] = w4;               // one b128 per lane
        int nrem = min(16, deg - base);
#pragma unroll 4
        for (int j = 0; j < nrem; j++) {            // 1 edge/group/step = 4 edges/wave
            int soff = srcS[g][j];
            float wv = wW[g][j][hl];
            uint2 hv = *(const uint2*)(h1b + (unsigned)(soff + laneoff));
            acc.x = fmaf(wv, bflo(hv.x), acc.x);
            acc.y = fmaf(wv, bfhi(hv.x), acc.y);
            acc.z = fmaf(wv, bflo(hv.y), acc.z);
            acc.w = fmaf(wv, bfhi(hv.y), acc.w);
        }
    }
    // group-local denominator reduce (xor of lane bits 0-3 stays in group)
#pragma unroll
    for (int off = 1; off <= 8; off <<= 1) {
        sac4.x += __shfl_xor(sac4.x, off);
        sac4.y += __shfl_xor(sac4.y, off);
        sac4.z += __shfl_xor(sac4.z, off);
        sac4.w += __shfl_xor(sac4.w, off);
    }
    float rins = 1.f / (selh(sac4, hl) + w0h);

    float4 bv = *(const float4*)&b1[gl << 2];
    float4 o4 = {acc.x * rins + bv.x, acc.y * rins + bv.y,
                 acc.z * rins + bv.z, acc.w * rins + bv.w};
    o4.x = (o4.x > 0.f) ? o4.x : expm1f(o4.x);      // ELU
    o4.y = (o4.y > 0.f) ? o4.y : expm1f(o4.y);
    o4.z = (o4.z > 0.f) ? o4.z : expm1f(o4.z);
    o4.w = (o4.w > 0.f) ? o4.w : expm1f(o4.w);
    *(float4*)&out_emb[node * C1 + (gl << 2)] = o4; // 16 lanes x 16B = full row

    // ---- fused layer-2 GEMM + attention dots (o4 stays in registers) ----
    __syncthreads();                                // w2S/aS2 staged by all threads
    int lane = tid & 63;
    int lbase = lane & 48;                          // my group's base lane in wave
    float gacc = 0.f;
#pragma unroll
    for (int m = 0; m < 16; m++) {                  // k = 4m..4m+3 lives in lane lbase+m
        float ox = __shfl(o4.x, lbase + m);
        float oy = __shfl(o4.y, lbase + m);
        float oz = __shfl(o4.z, lbase + m);
        float ow = __shfl(o4.w, lbase + m);
        gacc = fmaf(ox, w2S[(4 * m + 0) * NC + gl], gacc);
        gacc = fmaf(oy, w2S[(4 * m + 1) * NC + gl], gacc);
        gacc = fmaf(oz, w2S[(4 * m + 2) * NC + gl], gacc);
        gacc = fmaf(ow, w2S[(4 * m + 3) * NC + gl], gacc);
    }
    h2[node * NC + gl] = gacc;                      // tid-contiguous across block
    float ps = gacc * aS2[gl], pd = gacc * aD2[gl];
#pragma unroll
    for (int off = 1; off <= 8; off <<= 1) { ps += __shfl_xor(ps, off); pd += __shfl_xor(pd, off); }
    if (gl == 0) { a_src2[node] = ps; a_dst2[node] = pd; }
}

// ---------------- layer 2 softmax-aggregate + log_softmax --------------------
// RESTRUCTURED (round-4 lesson applied): 16-lane group per node, lane owns one
// class col. Weight phase all-lane-useful at deg~16; denominator/max/sum
// reductions are 4 shfl steps in-group; gather = 4B/lane over the node's 64B
// h2 row per group-step (same per-lane rate as the old wave shape, 1/4 the
// per-node fixed cost).
__global__ __launch_bounds__(256) void k_agg2(
    const float* __restrict__ h2, const float* __restrict__ a_src2,
    const float* __restrict__ a_dst2, const int* __restrict__ rowptr,
    const int* __restrict__ csr_src, const float* __restrict__ b2,
    float* __restrict__ out_lsm) {
    __shared__ int   srcS[16][17];                  // [group][edge] = h2 row byte off
    __shared__ float wS[16][17];                    // [group][edge] = weight
    int tid = threadIdx.x;
    int g  = tid >> 4;                              // group (0..15)
    int gl = tid & 15;                              // lane in group = class col
    int node = blockIdx.x * 16 + g;
    const char* h2b = (const char*)h2;
    int rs  = rowptr[node];
    int deg = rowptr[node + 1] - rs;

    float adst = a_dst2[node];                      // broadcast within group
    float w0 = __expf(lrelu(a_src2[node] + adst));
    float acc = w0 * h2[node * NC + gl];            // self contribution (64B/group)
    float sacc_l = 0.f;                             // per-lane partial denominator

    for (int base = 0; base < deg; base += 16) {
        int idx = base + gl;
        int s_l = 0; float w_l = 0.f;
        if (idx < deg) {                            // lane-parallel weight compute
            s_l = csr_src[rs + idx];
            w_l = __expf(lrelu(a_src2[s_l] + adst));
        }
        sacc_l += w_l;
        srcS[g][gl] = s_l << 6;                     // h2 row byte offset (64B)
        wS[g][gl] = w_l;
        int nrem = min(16, deg - base);
#pragma unroll 4
        for (int j = 0; j < nrem; j++) {            // 1 edge/group/step
            int soff = srcS[g][j];
            float wv = wS[g][j];
            float hv = *(const float*)(h2b + (unsigned)(soff + (gl << 2)));
            acc = fmaf(wv, hv, acc);
        }
    }
#pragma unroll
    for (int off = 1; off <= 8; off <<= 1)          // group-local denominator
        sacc_l += __shfl_xor(sacc_l, off);
    float sacc = sacc_l + w0;

    float logit = acc / sacc + b2[gl];
    float mxl = logit;
#pragma unroll
    for (int off = 1; off <= 8; off <<= 1) mxl = fmaxf(mxl, __shfl_xor(mxl, off));
    float ex = __expf(logit - mxl);
    float se = ex;
#pragma unroll
    for (int off = 1; off <= 8; off <<= 1) se += __shfl_xor(se, off);
    float lsm = (logit - mxl) - __logf(se);
    out_lsm[node * NC + gl] = lsm;                  // tid-contiguous across block
}

extern "C" void kernel_launch(void* const* d_in, const int* in_sizes, int n_in,
                              void* d_out, int out_size, void* d_ws, size_t ws_size,
                              hipStream_t stream) {
    const float* x   = (const float*)d_in[0];
    const int* ei    = (const int*)d_in[1];   // [2,E]: src row then dst row
    const float* W1  = (const float*)d_in[2];
    const float* as1 = (const float*)d_in[3];
    const float* ad1 = (const float*)d_in[4];
    const float* b1  = (const float*)d_in[5];
    const float* W2  = (const float*)d_in[6];
    const float* as2 = (const float*)d_in[7];
    const float* ad2 = (const float*)d_in[8];
    const float* b2  = (const float*)d_in[9];
    float* out = (float*)d_out;               // [N*16 log_softmax][N*64 embeddings]
    float* out_lsm = out;
    float* out_emb = out + (size_t)N_NODES * NC;

    float* ws = (float*)d_ws;
    unsigned* h1p = (unsigned*)ws;                   // N*32 u32 (bf16-packed rows)
    float* a_src1 = ws + (size_t)N_NODES * C1;       // N*4 (h1 slot reused, half free)
    float* a_dst1 = a_src1 + (size_t)N_NODES * 4;    // N*4
    float* h2     = a_dst1 + (size_t)N_NODES * 4;    // N*16
    float* a_src2 = h2     + (size_t)N_NODES * NC;   // N
    float* a_dst2 = a_src2 + (size_t)N_NODES;        // N
    int*   deg    = (int*)(a_dst2 + N_NODES);        // N
    int*   rowptr = deg + N_NODES;                   // N+1
    int*   cursor = rowptr + N_NODES + 1;            // N
    int*   csr    = cursor + N_NODES;                // E
    int*   partial= csr + N_EDGES;                   // SCAN_NB
    int*   pscan  = partial + SCAN_NB;               // SCAN_NB

    const int* e_src = ei;
    const int* e_dst = ei + N_EDGES;

    hipMemsetAsync(deg, 0, (size_t)N_NODES * sizeof(int), stream);

    k_hist_gemm1<<<GB1_NB, 256, 0, stream>>>(
        e_dst, deg, x, W1, as1, ad1, h1p, a_src1, a_dst1);

    k_scan1<<<SCAN_NB, 256, 0, stream>>>(deg, partial);
    k_scan2<<<1, 128, 0, stream>>>(partial, pscan, rowptr);
    k_scan3<<<SCAN_NB, 256, 0, stream>>>(deg, pscan, rowptr, cursor);

    k_scatter<<<HIST_NB, 256, 0, stream>>>(e_src, e_dst, cursor, csr);

    k_agg1 <<<N_NODES / 16, 256, 0, stream>>>(h1p, a_src1, a_dst1, rowptr, csr, b1,
                                              W2, as2, ad2, out_emb, h2, a_src2, a_dst2);
    k_agg2 <<<N_NODES / 16, 256, 0, stream>>>(h2, a_src2, a_dst2, rowptr, csr, b2, out_lsm);
}

// Round 10
// 305.197 us; speedup vs baseline: 1.3205x; 1.3205x over previous
//
#include <hip/hip_runtime.h>
#include <hip/hip_bf16.h>

#define N_NODES 100000
#define N_EDGES 1600000
#define IN_F 128
#define C1 64      // HEADS*HID
#define NC 16      // classes / layer2 width

#define SCAN_TILE 1024
#define SCAN_NB ((N_NODES + SCAN_TILE - 1) / SCAN_TILE)   // 98 blocks
#define GB1_NB (N_NODES / 32)                             // 3125 blocks, 32 nodes each
#define HIST_NB ((N_EDGES + 1023) / 1024)                 // 1563 (scatter grid)

typedef __attribute__((ext_vector_type(8))) short short8;
typedef __attribute__((ext_vector_type(4))) float f32x4;

__device__ __forceinline__ float lrelu(float x) { return fmaxf(x, 0.2f * x); }
__device__ __forceinline__ float selh(float4 v, int h) {
    return (h == 0) ? v.x : (h == 1) ? v.y : (h == 2) ? v.z : v.w;
}
// bf16 pack (round-to-nearest-even) / unpack helpers
__device__ __forceinline__ unsigned bf16pk(float a, float b) {
    unsigned ua = __float_as_uint(a), ub = __float_as_uint(b);
    ua = (ua + 0x7FFFu + ((ua >> 16) & 1u)) >> 16;
    ub = (ub + 0x7FFFu + ((ub >> 16) & 1u)) >> 16;
    return ua | (ub << 16);
}
__device__ __forceinline__ float bflo(unsigned u) { return __uint_as_float(u << 16); }
__device__ __forceinline__ float bfhi(unsigned u) { return __uint_as_float(u & 0xFFFF0000u); }

// ---------------- fused: histogram interleaved INTO layer1 MFMA GEMM ---------
// r8: returning atomics BEFORE the barrier -> vmcnt(0) drain ate 2 round-trips
// per wave before MFMA (77us). r9: moving the returning atomics to a bare
// scatter kernel was worse (140us, nothing to hide them). r10: atomics+rank
// stay HERE but move to the kernel TAIL — after barrier/MFMA/epilogue — so the
// ~800cy return-wait lands in the wave-retire window, overlapped across ~48
// waves/CU. e_dst loads issue at kernel start (done by tail time).
__global__ __launch_bounds__(256) void k_hist_gemm1(
    const int* __restrict__ e_dst, int* __restrict__ deg, int* __restrict__ rank,
    const float* __restrict__ x, const float* __restrict__ W1,
    const float* __restrict__ att_src1, const float* __restrict__ att_dst1,
    unsigned* __restrict__ h1p, float* __restrict__ a_src1, float* __restrict__ a_dst1) {
    __shared__ __align__(16) unsigned xBSu[32 * 68];   // 8.7 KB: [32 rows][68 u32 = 136 bf16]
    __shared__ __align__(16) unsigned wTu[64 * 68];    // 17.4 KB: [64 cols][68 u32 = 136 bf16]
    int tid = threadIdx.x;

    // ---- edge dst loads issue early (atomics deferred to tail)
    int e0 = blockIdx.x * 512 + tid;
    int d0 = e_dst[e0];
    int d1 = e_dst[e0 + 256];

    int node0 = blockIdx.x * 32;

    // ---- stage x tile (32 rows x 128) -> bf16
#pragma unroll
    for (int ii = 0; ii < 4; ii++) {                // 1024 float4s, 4/thread
        int i = tid + ii * 256;
        int r = i >> 5, c4 = (i & 31) << 2;         // c4 = k, multiple of 4
        float4 v = *(const float4*)&x[(node0 + r) * IN_F + c4];
        *(uint2*)&xBSu[r * 68 + (c4 >> 1)] =
            make_uint2(bf16pk(v.x, v.y), bf16pk(v.z, v.w));
    }
    // ---- stage W1 transposed -> bf16: wT[col][k], u32 kp holds k=2kp,2kp+1
#pragma unroll
    for (int ii = 0; ii < 4; ii++) {
        int kp = (tid >> 4) + ii * 16;              // k-pair 0..63
        int n0 = (tid & 15) << 2;
        int k = kp << 1;
        float4 r0 = *(const float4*)&W1[k * C1 + n0];
        float4 r1 = *(const float4*)&W1[(k + 1) * C1 + n0];
        wTu[(n0 + 0) * 68 + kp] = bf16pk(r0.x, r1.x);
        wTu[(n0 + 1) * 68 + kp] = bf16pk(r0.y, r1.y);
        wTu[(n0 + 2) * 68 + kp] = bf16pk(r0.z, r1.z);
        wTu[(n0 + 3) * 68 + kp] = bf16pk(r0.w, r1.w);
    }
    __syncthreads();

    // ---- MFMA K-loop: wave (wm,wn): rows 16*wm.., cols 32*wn..
    int wid = tid >> 6, l = tid & 63;
    int wm = wid & 1, wn = wid >> 1;
    int myc = l & 15;
    int koff = (l >> 4) << 3;                       // 8*(l>>4)
    const unsigned short* xu = (const unsigned short*)xBSu;
    const unsigned short* wu = (const unsigned short*)wTu;
    int arow = 16 * wm + myc;
    int bcol = 32 * wn + myc;
    f32x4 acc0 = {0.f, 0.f, 0.f, 0.f}, acc1 = acc0;
#pragma unroll
    for (int ks = 0; ks < 4; ks++) {
        int k0 = ks * 32 + koff;
        short8 af  = *(const short8*)&xu[arow * 136 + k0];
        short8 bf0 = *(const short8*)&wu[bcol * 136 + k0];
        short8 bf1 = *(const short8*)&wu[(bcol + 16) * 136 + k0];
        acc0 = __builtin_amdgcn_mfma_f32_16x16x32_bf16(af, bf0, acc0, 0, 0, 0);
        acc1 = __builtin_amdgcn_mfma_f32_16x16x32_bf16(af, bf1, acc1, 0, 0, 0);
    }

    // ---- epilogue from C frags: h1p bf16 pack + att dots (per-head = per-tile)
    int rbase = (l >> 4) << 2;
#pragma unroll
    for (int t = 0; t < 2; t++) {
        f32x4 av = t ? acc1 : acc0;
        int cb = 32 * wn + 16 * t;                  // tile col base; head = cb/16
        int head = cb >> 4;
        float sv = att_src1[cb + myc];
        float dv = att_dst1[cb + myc];
#pragma unroll
        for (int i = 0; i < 4; i++) {
            float v = av[i];
            int node = node0 + 16 * wm + rbase + i;
            float vp = __shfl_xor(v, 1);            // partner col's value
            if ((l & 1) == 0)
                h1p[node * 32 + (cb >> 1) + (myc >> 1)] = bf16pk(v, vp);
            float ps = v * sv, pd = v * dv;
            ps += __shfl_xor(ps, 1); ps += __shfl_xor(ps, 2);
            ps += __shfl_xor(ps, 4); ps += __shfl_xor(ps, 8);
            pd += __shfl_xor(pd, 1); pd += __shfl_xor(pd, 2);
            pd += __shfl_xor(pd, 4); pd += __shfl_xor(pd, 8);
            if (myc == 0) {
                a_src1[node * 4 + head] = ps;
                a_dst1[node * 4 + head] = pd;
            }
        }
    }

    // ---- tail: returning atomics + rank stores (no barrier after -> the
    // return-wait overlaps across retiring waves instead of stalling MFMA)
    int rk0 = atomicAdd(&deg[d0], 1);
    int rk1 = atomicAdd(&deg[d1], 1);
    rank[e0] = rk0;
    rank[e0 + 256] = rk1;
}

// pass 1: per-block sums of deg (1024 elems per 256-thread block)
__global__ __launch_bounds__(256) void k_scan1(const int* __restrict__ deg,
                                               int* __restrict__ partial) {
    __shared__ int wsum[4];
    int tid = threadIdx.x;
    int i0 = blockIdx.x * SCAN_TILE + tid * 4;
    int s = 0;
#pragma unroll
    for (int j = 0; j < 4; j++) { int i = i0 + j; if (i < N_NODES) s += deg[i]; }
    for (int off = 32; off; off >>= 1) s += __shfl_xor(s, off);
    if ((tid & 63) == 0) wsum[tid >> 6] = s;
    __syncthreads();
    if (tid == 0) partial[blockIdx.x] = wsum[0] + wsum[1] + wsum[2] + wsum[3];
}

// pass 2: exclusive scan of the 98 partials (single tiny block)
__global__ void k_scan2(const int* __restrict__ partial, int* __restrict__ pscan,
                        int* __restrict__ rowptr) {
    __shared__ int buf[128];
    int tid = threadIdx.x;
    int v = (tid < SCAN_NB) ? partial[tid] : 0;
    buf[tid] = v;
    __syncthreads();
    for (int d = 1; d < 128; d <<= 1) {
        int t = (tid >= d) ? buf[tid - d] : 0;
        __syncthreads();
        buf[tid] += t;
        __syncthreads();
    }
    if (tid < SCAN_NB) pscan[tid] = buf[tid] - v;    // exclusive
    if (tid == 0) rowptr[N_NODES] = N_EDGES;         // total is static
}

// pass 3: block-local exclusive scan + block offset -> rowptr
__global__ __launch_bounds__(256) void k_scan3(const int* __restrict__ deg,
                                               const int* __restrict__ pscan,
                                               int* __restrict__ rowptr) {
    __shared__ int wsum[4];
    int tid = threadIdx.x, lane = tid & 63, wave = tid >> 6;
    int i0 = blockIdx.x * SCAN_TILE + tid * 4;
    int v0 = 0, v1 = 0, v2 = 0, v3 = 0;
    if (i0 + 0 < N_NODES) v0 = deg[i0 + 0];
    if (i0 + 1 < N_NODES) v1 = deg[i0 + 1];
    if (i0 + 2 < N_NODES) v2 = deg[i0 + 2];
    if (i0 + 3 < N_NODES) v3 = deg[i0 + 3];
    int s0 = v0, s1 = s0 + v1, s2 = s1 + v2, s3 = s2 + v3;   // thread-local inclusive
    int t = s3;                                              // wave inclusive scan
    for (int off = 1; off < 64; off <<= 1) {
        int u = __shfl_up(t, off);
        if (lane >= off) t += u;
    }
    if (lane == 63) wsum[wave] = t;
    __syncthreads();
    int woff = 0;
    for (int w = 0; w < wave; w++) woff += wsum[w];
    int base = pscan[blockIdx.x] + woff + (t - s3);          // exclusive prefix
    if (i0 + 0 < N_NODES) rowptr[i0 + 0] = base;
    if (i0 + 1 < N_NODES) rowptr[i0 + 1] = base + s0;
    if (i0 + 2 < N_NODES) rowptr[i0 + 2] = base + s1;
    if (i0 + 3 < N_NODES) rowptr[i0 + 3] = base + s2;
}

// atomic-free scatter: rank was captured during hist (r8 form, proven ~45us)
__global__ __launch_bounds__(256) void k_scatter(
    const int* __restrict__ e_src, const int* __restrict__ e_dst,
    const int* __restrict__ rank, const int* __restrict__ rowptr,
    int* __restrict__ csr_src) {
    int e0 = blockIdx.x * 1024 + threadIdx.x;
#pragma unroll
    for (int j = 0; j < 4; j++) {
        int e = e0 + j * 256;
        if (e < N_EDGES)
            csr_src[rowptr[e_dst[e]] + rank[e]] = e_src[e];
    }
}

// ---------------- layer 1 segment-softmax + aggregate ------------------------
// 16-lane group per node; packed-bf16 h1 gather (8B/lane). Unchanged from r7.
__global__ __launch_bounds__(256) void k_agg1(
    const unsigned* __restrict__ h1p, const float* __restrict__ a_src1,
    const float* __restrict__ a_dst1, const int* __restrict__ rowptr,
    const int* __restrict__ csr_src, const float* __restrict__ b1,
    const float* __restrict__ W2, const float* __restrict__ att_src2,
    const float* __restrict__ att_dst2,
    float* __restrict__ out_emb, float* __restrict__ h2,
    float* __restrict__ a_src2, float* __restrict__ a_dst2) {
    __shared__ int   srcS[16][17];                 // [group][edge] = src row byte off
    __shared__ __align__(16) float wW[16][17][4];  // [group][edge][head]
    __shared__ __align__(16) float w2S[C1 * NC];   // 4 KB [k][c]
    __shared__ float aS2[NC], aD2[NC];
    int tid = threadIdx.x;
    int g  = tid >> 4;                              // group in block (0..15)
    int gl = tid & 15;                              // lane in group
    int hl = gl >> 2;                               // head of my 4 owned cols
    int node = blockIdx.x * 16 + g;
    const char* h1b = (const char*)h1p;
    int laneoff = gl << 3;                          // byte offset of my 4 bf16 cols

    if (tid < (C1 * NC) / 4)
        *(float4*)&w2S[tid * 4] = *(const float4*)&W2[tid * 4];
    if (tid < NC) { aS2[tid] = att_src2[tid]; aD2[tid] = att_dst2[tid]; }

    int rs  = rowptr[node];
    int deg = rowptr[node + 1] - rs;

    float4 ad4 = *(const float4*)&a_dst1[node * 4];  // broadcast within group
    float w0h = __expf(lrelu(a_src1[node * 4 + hl] + selh(ad4, hl)));  // self weight, my head

    uint2 sp = *(const uint2*)(h1b + (unsigned)(node * 128 + laneoff));
    float4 acc = {w0h * bflo(sp.x), w0h * bfhi(sp.x),
                  w0h * bflo(sp.y), w0h * bfhi(sp.y)};
    float4 sac4 = {0.f, 0.f, 0.f, 0.f};             // per-lane partial denominator

    for (int base = 0; base < deg; base += 16) {    // 16 edges per group-chunk
        int idx = base + gl;
        int s_l = 0;
        float4 w4 = {0.f, 0.f, 0.f, 0.f};
        if (idx < deg) {                            // lane-parallel weight compute
            s_l = csr_src[rs + idx];
            float4 as = *(const float4*)&a_src1[s_l * 4];
            w4.x = __expf(lrelu(as.x + ad4.x));
            w4.y = __expf(lrelu(as.y + ad4.y));
            w4.z = __expf(lrelu(as.z + ad4.z));
            w4.w = __expf(lrelu(as.w + ad4.w));
        }
        sac4.x += w4.x; sac4.y += w4.y; sac4.z += w4.z; sac4.w += w4.w;
        srcS[g][gl] = s_l << 7;                     // bf16 row byte offset (128B)
        *(float4*)&wW[g][gl][0] = w4;               // one b128 per lane
        int nrem = min(16, deg - base);
#pragma unroll 4
        for (int j = 0; j < nrem; j++) {            // 1 edge/group/step = 4 edges/wave
            int soff = srcS[g][j];
            float wv = wW[g][j][hl];
            uint2 hv = *(const uint2*)(h1b + (unsigned)(soff + laneoff));
            acc.x = fmaf(wv, bflo(hv.x), acc.x);
            acc.y = fmaf(wv, bfhi(hv.x), acc.y);
            acc.z = fmaf(wv, bflo(hv.y), acc.z);
            acc.w = fmaf(wv, bfhi(hv.y), acc.w);
        }
    }
    // group-local denominator reduce (xor of lane bits 0-3 stays in group)
#pragma unroll
    for (int off = 1; off <= 8; off <<= 1) {
        sac4.x += __shfl_xor(sac4.x, off);
        sac4.y += __shfl_xor(sac4.y, off);
        sac4.z += __shfl_xor(sac4.z, off);
        sac4.w += __shfl_xor(sac4.w, off);
    }
    float rins = 1.f / (selh(sac4, hl) + w0h);

    float4 bv = *(const float4*)&b1[gl << 2];
    float4 o4 = {acc.x * rins + bv.x, acc.y * rins + bv.y,
                 acc.z * rins + bv.z, acc.w * rins + bv.w};
    o4.x = (o4.x > 0.f) ? o4.x : expm1f(o4.x);      // ELU
    o4.y = (o4.y > 0.f) ? o4.y : expm1f(o4.y);
    o4.z = (o4.z > 0.f) ? o4.z : expm1f(o4.z);
    o4.w = (o4.w > 0.f) ? o4.w : expm1f(o4.w);
    *(float4*)&out_emb[node * C1 + (gl << 2)] = o4; // 16 lanes x 16B = full row

    // ---- fused layer-2 GEMM + attention dots (o4 stays in registers) ----
    __syncthreads();                                // w2S/aS2 staged by all threads
    int lane = tid & 63;
    int lbase = lane & 48;                          // my group's base lane in wave
    float gacc = 0.f;
#pragma unroll
    for (int m = 0; m < 16; m++) {                  // k = 4m..4m+3 lives in lane lbase+m
        float ox = __shfl(o4.x, lbase + m);
        float oy = __shfl(o4.y, lbase + m);
        float oz = __shfl(o4.z, lbase + m);
        float ow = __shfl(o4.w, lbase + m);
        gacc = fmaf(ox, w2S[(4 * m + 0) * NC + gl], gacc);
        gacc = fmaf(oy, w2S[(4 * m + 1) * NC + gl], gacc);
        gacc = fmaf(oz, w2S[(4 * m + 2) * NC + gl], gacc);
        gacc = fmaf(ow, w2S[(4 * m + 3) * NC + gl], gacc);
    }
    h2[node * NC + gl] = gacc;                      // tid-contiguous across block
    float ps = gacc * aS2[gl], pd = gacc * aD2[gl];
#pragma unroll
    for (int off = 1; off <= 8; off <<= 1) { ps += __shfl_xor(ps, off); pd += __shfl_xor(pd, off); }
    if (gl == 0) { a_src2[node] = ps; a_dst2[node] = pd; }
}

// ---------------- layer 2 softmax-aggregate + log_softmax --------------------
// 16-lane group per node (r9, verified): weight phase all-lane-useful at
// deg~16, 4-step group reductions, 4B/lane gather over the node's 64B h2 row.
__global__ __launch_bounds__(256) void k_agg2(
    const float* __restrict__ h2, const float* __restrict__ a_src2,
    const float* __restrict__ a_dst2, const int* __restrict__ rowptr,
    const int* __restrict__ csr_src, const float* __restrict__ b2,
    float* __restrict__ out_lsm) {
    __shared__ int   srcS[16][17];                  // [group][edge] = h2 row byte off
    __shared__ float wS[16][17];                    // [group][edge] = weight
    int tid = threadIdx.x;
    int g  = tid >> 4;                              // group (0..15)
    int gl = tid & 15;                              // lane in group = class col
    int node = blockIdx.x * 16 + g;
    const char* h2b = (const char*)h2;
    int rs  = rowptr[node];
    int deg = rowptr[node + 1] - rs;

    float adst = a_dst2[node];                      // broadcast within group
    float w0 = __expf(lrelu(a_src2[node] + adst));
    float acc = w0 * h2[node * NC + gl];            // self contribution (64B/group)
    float sacc_l = 0.f;                             // per-lane partial denominator

    for (int base = 0; base < deg; base += 16) {
        int idx = base + gl;
        int s_l = 0; float w_l = 0.f;
        if (idx < deg) {                            // lane-parallel weight compute
            s_l = csr_src[rs + idx];
            w_l = __expf(lrelu(a_src2[s_l] + adst));
        }
        sacc_l += w_l;
        srcS[g][gl] = s_l << 6;                     // h2 row byte offset (64B)
        wS[g][gl] = w_l;
        int nrem = min(16, deg - base);
#pragma unroll 4
        for (int j = 0; j < nrem; j++) {            // 1 edge/group/step
            int soff = srcS[g][j];
            float wv = wS[g][j];
            float hv = *(const float*)(h2b + (unsigned)(soff + (gl << 2)));
            acc = fmaf(wv, hv, acc);
        }
    }
#pragma unroll
    for (int off = 1; off <= 8; off <<= 1)          // group-local denominator
        sacc_l += __shfl_xor(sacc_l, off);
    float sacc = sacc_l + w0;

    float logit = acc / sacc + b2[gl];
    float mxl = logit;
#pragma unroll
    for (int off = 1; off <= 8; off <<= 1) mxl = fmaxf(mxl, __shfl_xor(mxl, off));
    float ex = __expf(logit - mxl);
    float se = ex;
#pragma unroll
    for (int off = 1; off <= 8; off <<= 1) se += __shfl_xor(se, off);
    float lsm = (logit - mxl) - __logf(se);
    out_lsm[node * NC + gl] = lsm;                  // tid-contiguous across block
}

extern "C" void kernel_launch(void* const* d_in, const int* in_sizes, int n_in,
                              void* d_out, int out_size, void* d_ws, size_t ws_size,
                              hipStream_t stream) {
    const float* x   = (const float*)d_in[0];
    const int* ei    = (const int*)d_in[1];   // [2,E]: src row then dst row
    const float* W1  = (const float*)d_in[2];
    const float* as1 = (const float*)d_in[3];
    const float* ad1 = (const float*)d_in[4];
    const float* b1  = (const float*)d_in[5];
    const float* W2  = (const float*)d_in[6];
    const float* as2 = (const float*)d_in[7];
    const float* ad2 = (const float*)d_in[8];
    const float* b2  = (const float*)d_in[9];
    float* out = (float*)d_out;               // [N*16 log_softmax][N*64 embeddings]
    float* out_lsm = out;
    float* out_emb = out + (size_t)N_NODES * NC;

    float* ws = (float*)d_ws;
    unsigned* h1p = (unsigned*)ws;                   // N*32 u32 (bf16-packed rows)
    float* a_src1 = ws + (size_t)N_NODES * C1;       // N*4 (h1 slot reused, half free)
    float* a_dst1 = a_src1 + (size_t)N_NODES * 4;    // N*4
    float* h2     = a_dst1 + (size_t)N_NODES * 4;    // N*16
    float* a_src2 = h2     + (size_t)N_NODES * NC;   // N
    float* a_dst2 = a_src2 + (size_t)N_NODES;        // N
    int*   deg    = (int*)(a_dst2 + N_NODES);        // N
    int*   rowptr = deg + N_NODES;                   // N+1
    int*   csr    = rowptr + N_NODES + 1;            // E
    int*   rank   = csr + N_EDGES;                   // E
    int*   partial= rank + N_EDGES;                  // SCAN_NB
    int*   pscan  = partial + SCAN_NB;               // SCAN_NB

    const int* e_src = ei;
    const int* e_dst = ei + N_EDGES;

    hipMemsetAsync(deg, 0, (size_t)N_NODES * sizeof(int), stream);

    k_hist_gemm1<<<GB1_NB, 256, 0, stream>>>(
        e_dst, deg, rank, x, W1, as1, ad1, h1p, a_src1, a_dst1);

    k_scan1<<<SCAN_NB, 256, 0, stream>>>(deg, partial);
    k_scan2<<<1, 128, 0, stream>>>(partial, pscan, rowptr);
    k_scan3<<<SCAN_NB, 256, 0, stream>>>(deg, pscan, rowptr);

    k_scatter<<<HIST_NB, 256, 0, stream>>>(e_src, e_dst, rank, rowptr, csr);

    k_agg1 <<<N_NODES / 16, 256, 0, stream>>>(h1p, a_src1, a_dst1, rowptr, csr, b1,
                                              W2, as2, ad2, out_emb, h2, a_src2, a_dst2);
    k_agg2 <<<N_NODES / 16, 256, 0, stream>>>(h2, a_src2, a_dst2, rowptr, csr, b2, out_lsm);
}